// Round 1
// baseline (653.183 us; speedup 1.0000x reference)
//
#include <hip/hip_runtime.h>

// AttnPool3D: logits = feat·w + 2*clip(mask,0,1); w = softmax_n(logits); out[b,c] = Σ_n feat*w
// Shapes fixed by setup_inputs(): B=2, C=128, D*H*W = N = 442368, all fp32.
constexpr int C   = 128;
constexpr int N   = 48 * 96 * 96;   // 442368
constexpr int B   = 2;
constexpr int NPB = 256;            // positions per block (== blockDim.x)
constexpr int BPB = N / NPB;        // 1728 blocks per batch (exact)
constexpr int REC = 132;            // per-block record: [m, l, pad, pad, S[0..127]]

// One DPP reduce step: x += dpp_move(x). old=0 so masked-off rows add 0.
template <int CTRL, int RM>
__device__ __forceinline__ float dpp_add_step(float x) {
    int y = __builtin_amdgcn_update_dpp(0, __float_as_int(x), CTRL, RM, 0xF, true);
    return x + __int_as_float(y);
}

// Full 64-lane sum; result valid in lanes 48..63 (we read lane 63).
// All steps are VALU (DPP), keeping the per-CU LDS/DS pipe free — we do 128 of
// these per wave, so ds_bpermute-based __shfl would become the bottleneck.
__device__ __forceinline__ float wave_sum64(float x) {
    x = dpp_add_step<0xB1, 0xF>(x);   // quad_perm [1,0,3,2]  (xor 1)
    x = dpp_add_step<0x4E, 0xF>(x);   // quad_perm [2,3,0,1]  (xor 2)
    x = dpp_add_step<0x141, 0xF>(x);  // row_half_mirror      (xor within 8)
    x = dpp_add_step<0x140, 0xF>(x);  // row_mirror           (xor within 16)
    x = dpp_add_step<0x142, 0xA>(x);  // row_bcast15 -> rows 1,3
    x = dpp_add_step<0x143, 0xC>(x);  // row_bcast31 -> rows 2,3
    return x;
}

__global__ __launch_bounds__(256, 3) void attn_pool_pass1(
    const float* __restrict__ feat, const float* __restrict__ mask,
    const float* __restrict__ w, float* __restrict__ rec)
{
    const int tid = threadIdx.x;
    const int blk = blockIdx.x;
    const int b   = blk / BPB;
    const int n   = (blk % BPB) * NPB + tid;

    const float* fp = feat + (size_t)b * C * N + n;

    // Cache all 128 channel values for this position in VGPRs (read feat ONCE).
    float f[C];
    float logit = 0.f;
#pragma unroll
    for (int c = 0; c < C; ++c) {
        f[c] = fp[(size_t)c * N];          // coalesced: lanes read consecutive n
        logit = fmaf(f[c], w[c], logit);   // w[c] is a uniform (scalar) load
    }
    float mv = mask[(size_t)b * N + n];
    mv = fminf(fmaxf(mv, 0.f), 1.f);
    logit += 2.0f * mv;

    const int lane = tid & 63;
    const int wv   = tid >> 6;
    __shared__ float rmax[4];
    __shared__ float rsum[4];
    __shared__ float SRed[4][C];

    // block max of logits
    float m = logit;
#pragma unroll
    for (int off = 32; off; off >>= 1) m = fmaxf(m, __shfl_xor(m, off, 64));
    if (lane == 0) rmax[wv] = m;
    __syncthreads();
    m = fmaxf(fmaxf(rmax[0], rmax[1]), fmaxf(rmax[2], rmax[3]));

    // p and block sum of p
    const float p = __expf(logit - m);
    float l = p;
#pragma unroll
    for (int off = 32; off; off >>= 1) l += __shfl_xor(l, off, 64);
    if (lane == 0) rsum[wv] = l;

    // per-channel weighted sums S_c = sum_n f[c]*p  (wave DPP reduce, lane 63 owns result)
    const bool lastlane = (lane == 63);
#pragma unroll
    for (int c = 0; c < C; ++c) {
        float v = wave_sum64(f[c] * p);
        if (lastlane) SRed[wv][c] = v;
    }
    __syncthreads();

    float* out = rec + (size_t)blk * REC;
    if (tid < C) {
        out[4 + tid] = SRed[0][tid] + SRed[1][tid] + SRed[2][tid] + SRed[3][tid];
    } else if (tid == C) {
        out[0] = m;
        out[1] = rsum[0] + rsum[1] + rsum[2] + rsum[3];
    }
}

__global__ __launch_bounds__(256) void attn_pool_pass2(
    const float* __restrict__ rec, float* __restrict__ out)
{
    const int b    = blockIdx.x;
    const int tid  = threadIdx.x;
    const int lane = tid & 63;
    const int wv   = tid >> 6;
    const float* base = rec + (size_t)b * BPB * REC;

    __shared__ float sc[BPB];   // per-block rescale factors e^{m_blk - M}
    __shared__ float r4[4];
    __shared__ float racc[C];

    // global max M over block maxima
    float m = -3.4e38f;
    for (int i = tid; i < BPB; i += 256) m = fmaxf(m, base[(size_t)i * REC]);
#pragma unroll
    for (int off = 32; off; off >>= 1) m = fmaxf(m, __shfl_xor(m, off, 64));
    if (lane == 0) r4[wv] = m;
    __syncthreads();
    const float M = fmaxf(fmaxf(r4[0], r4[1]), fmaxf(r4[2], r4[3]));
    __syncthreads();  // r4 reused for Z below

    // Z = sum_blk l_blk * e^{m_blk - M}; cache scales in LDS
    float z = 0.f;
    for (int i = tid; i < BPB; i += 256) {
        float e = __expf(base[(size_t)i * REC] - M);
        sc[i] = e;
        z = fmaf(base[(size_t)i * REC + 1], e, z);
    }
#pragma unroll
    for (int off = 32; off; off >>= 1) z += __shfl_xor(z, off, 64);
    if (lane == 0) r4[wv] = z;
    __syncthreads();
    const float Z = r4[0] + r4[1] + r4[2] + r4[3];

    // out[b,c] = (sum_blk S_blk[c] * e^{m_blk - M}) / Z ; 2 threads per channel
    const int c    = tid & (C - 1);
    const int half = tid >> 7;
    float acc = 0.f;
    const int i0 = half * (BPB / 2), i1 = i0 + (BPB / 2);
    for (int i = i0; i < i1; ++i)
        acc = fmaf(base[(size_t)i * REC + 4 + c], sc[i], acc);
    if (half == 1) racc[c] = acc;
    __syncthreads();
    if (half == 0) out[b * C + c] = (acc + racc[c]) / Z;
}

extern "C" void kernel_launch(void* const* d_in, const int* in_sizes, int n_in,
                              void* d_out, int out_size, void* d_ws, size_t ws_size,
                              hipStream_t stream)
{
    const float* feat = (const float*)d_in[0];
    const float* mask = (const float*)d_in[1];
    const float* w    = (const float*)d_in[2];
    float* rec = (float*)d_ws;   // needs B*BPB*REC*4 = ~1.83 MB of scratch

    attn_pool_pass1<<<B * BPB, 256, 0, stream>>>(feat, mask, w, rec);
    attn_pool_pass2<<<B, 256, 0, stream>>>(rec, (float*)d_out);
}